// Round 1
// baseline (172.034 us; speedup 1.0000x reference)
//
#include <hip/hip_runtime.h>
#include <math.h>

// Problem constants (from reference): B=16, C=512, H=W=62, HW=3844,
// 9 regions, 5 negatives/region, TEMP=0.1, EPS=1e-6.
#define NPAIR 8
#define NREG 9
#define NCH 512
#define HW 3844
#define W62 62

// Flat patch base indices (row*62+col) precomputed from POS / NEG tables.
__constant__ int POS_BASE[9] = {0, 30, 60, 1860, 1890, 1920, 3720, 3750, 3780};
__constant__ int NEG_BASE[9][5] = {
    {30, 1860, 1890, 60, 3720},
    {0, 60, 1860, 1890, 1920},
    {0, 30, 1890, 1920, 3780},
    {0, 30, 1890, 3720, 3750},
    {0, 30, 1860, 1920, 3750},
    {30, 60, 1890, 3750, 3780},
    {0, 1860, 1890, 3750, 3780},
    {1860, 1890, 1920, 3720, 3780},
    {60, 1890, 1920, 3720, 3750}};

__device__ __forceinline__ void load_patch(const float* __restrict__ p, int base, float v[4]) {
    // patch = [base, base+1, base+62, base+63]; all bases are even -> 8B aligned
    float2 a = *(const float2*)(p + base);
    float2 b = *(const float2*)(p + base + W62);
    v[0] = a.x; v[1] = a.y; v[2] = b.x; v[3] = b.y;
}

__device__ __forceinline__ float dot4(const float* a, const float* b) {
    return a[0] * b[0] + a[1] * b[1] + a[2] * b[2] + a[3] * b[3];
}

__device__ __forceinline__ float wave_sum(float v) {
    #pragma unroll
    for (int off = 32; off > 0; off >>= 1) v += __shfl_down(v, off, 64);
    return v;
}

// One block per (pair, region): 512 threads = 512 channels.
// Emits per-(pair,region) loss term log(S+D1)+log(S+D2)-2*log(S) to ws.
__global__ __launch_bounds__(512) void lcl_partial(const float* __restrict__ x,
                                                   float* __restrict__ ws) {
    const int blk = blockIdx.x;       // 0..71
    const int p = blk / NREG;
    const int r = blk % NREG;
    const int c = threadIdx.x;        // channel

    const float* p1 = x + ((size_t)(2 * p) * NCH + c) * HW;
    const float* p2 = x + ((size_t)(2 * p + 1) * NCH + c) * HW;

    float v1[4], v2[4], n1[5][4], n2[5][4];
    const int pb = POS_BASE[r];
    load_patch(p1, pb, v1);
    load_patch(p2, pb, v2);
    #pragma unroll
    for (int j = 0; j < 5; j++) {
        const int nb = NEG_BASE[r][j];
        load_patch(p1, nb, n1[j]);
        load_patch(p2, nb, n2[j]);
    }

    const float nv1 = dot4(v1, v1);
    const float nv2 = dot4(v2, v2);

    float s = expf(10.0f * dot4(v1, v2) / fmaxf(sqrtf(nv1 * nv2), 1e-6f));
    float d1 = 0.0f, d2 = 0.0f;
    #pragma unroll
    for (int j = 0; j < 5; j++) {
        const float nn1 = dot4(n1[j], n1[j]);
        const float nn2 = dot4(n2[j], n2[j]);
        d1 += expf(10.0f * dot4(v1, n1[j]) / fmaxf(sqrtf(nv1 * nn1), 1e-6f));
        d1 += expf(10.0f * dot4(v1, n2[j]) / fmaxf(sqrtf(nv1 * nn2), 1e-6f));
        d2 += expf(10.0f * dot4(v2, n2[j]) / fmaxf(sqrtf(nv2 * nn2), 1e-6f));
        d2 += expf(10.0f * dot4(v2, n1[j]) / fmaxf(sqrtf(nv2 * nn1), 1e-6f));
    }

    // Block reduction: wave shuffle then LDS across the 8 waves.
    s = wave_sum(s);
    d1 = wave_sum(d1);
    d2 = wave_sum(d2);

    __shared__ float sm[3][8];
    const int wave = threadIdx.x >> 6;
    const int lane = threadIdx.x & 63;
    if (lane == 0) { sm[0][wave] = s; sm[1][wave] = d1; sm[2][wave] = d2; }
    __syncthreads();
    if (threadIdx.x == 0) {
        float S = 0.0f, D1 = 0.0f, D2 = 0.0f;
        #pragma unroll
        for (int w = 0; w < 8; w++) { S += sm[0][w]; D1 += sm[1][w]; D2 += sm[2][w]; }
        ws[blk] = logf(S + D1) + logf(S + D2) - 2.0f * logf(S);
    }
}

// Reduce the 72 partial terms -> scalar loss (/ B / N_REGIONS = /144).
__global__ __launch_bounds__(64) void lcl_final(const float* __restrict__ ws,
                                                float* __restrict__ out) {
    const int t = threadIdx.x;  // 0..63
    float v = ws[t];
    if (t + 64 < NPAIR * NREG) v += ws[t + 64];
    v = wave_sum(v);
    if (t == 0) out[0] = v * (1.0f / 144.0f);
}

extern "C" void kernel_launch(void* const* d_in, const int* in_sizes, int n_in,
                              void* d_out, int out_size, void* d_ws, size_t ws_size,
                              hipStream_t stream) {
    const float* x = (const float*)d_in[0];
    float* out = (float*)d_out;
    float* ws = (float*)d_ws;  // needs 72 floats

    lcl_partial<<<NPAIR * NREG, 512, 0, stream>>>(x, ws);
    lcl_final<<<1, 64, 0, stream>>>(ws, out);
}

// Round 2
// 161.657 us; speedup vs baseline: 1.0642x; 1.0642x over previous
//
#include <hip/hip_runtime.h>
#include <math.h>

// B=16, C=512, H=W=62, HW=3844, 9 regions, 5 negs/region, TEMP=0.1, EPS=1e-6.
#define NPAIR 8
#define NREG 9
#define NCH 512
#define HW 3844
#define W62 62
#define NPATCH 9

// The 9 unique patch base offsets (row*62+col). POS region r uses patch r;
// NEG bases are a subset of the same 9 -> indices below.
__constant__ int PATCH_BASE[9] = {0, 30, 60, 1860, 1890, 1920, 3720, 3750, 3780};
__constant__ int NEG_IDX[9][5] = {
    {1, 3, 4, 2, 6},
    {0, 2, 3, 4, 5},
    {0, 1, 4, 5, 8},
    {0, 1, 4, 6, 7},
    {0, 1, 3, 5, 7},
    {1, 2, 4, 7, 8},
    {0, 3, 4, 7, 8},
    {3, 4, 5, 6, 8},
    {2, 4, 5, 6, 7}};

#define G_FLOATS (16 * NPATCH * 4 * NCH)  // 294912 floats = 1.18 MB

__device__ __forceinline__ float dot4(const float* a, const float* b) {
    return a[0] * b[0] + a[1] * b[1] + a[2] * b[2] + a[3] * b[3];
}

__device__ __forceinline__ float wave_sum(float v) {
    #pragma unroll
    for (int off = 32; off > 0; off >>= 1) v += __shfl_down(v, off, 64);
    return v;
}

// Phase A: gather the 36 used pixels of each (b,c) plane into compact,
// channel-innermost layout g[b][patch][k][c]. One thread per (b,patch,c):
// 73728 threads, each unique 64B line of x touched exactly once.
__global__ __launch_bounds__(256) void lcl_gather(const float* __restrict__ x,
                                                  float* __restrict__ g) {
    const int tid = blockIdx.x * 256 + threadIdx.x;  // 0..73727
    const int c = tid & (NCH - 1);
    const int bp = tid >> 9;            // b*9 + patch
    const int patch = bp % NPATCH;
    const int b = bp / NPATCH;
    const float* src = x + (size_t)(b * NCH + c) * HW + PATCH_BASE[patch];
    const float2 a0 = *(const float2*)(src);
    const float2 a1 = *(const float2*)(src + W62);
    float* dst = g + (size_t)bp * 4 * NCH + c;
    dst[0] = a0.x;
    dst[NCH] = a0.y;
    dst[2 * NCH] = a1.x;
    dst[3 * NCH] = a1.y;
}

// Phase B: one block per (pair, region), thread = channel. All reads from g
// are coalesced (stride-1 in c) and L2-resident.
__global__ __launch_bounds__(512) void lcl_partial(const float* __restrict__ g,
                                                   float* __restrict__ terms) {
    const int blk = blockIdx.x;  // 0..71
    const int p = blk / NREG;
    const int r = blk % NREG;
    const int c = threadIdx.x;

    const float* g1 = g + (size_t)(2 * p) * NPATCH * 4 * NCH + c;
    const float* g2 = g + (size_t)(2 * p + 1) * NPATCH * 4 * NCH + c;

    float v1[4], v2[4], n1[5][4], n2[5][4];
    #pragma unroll
    for (int k = 0; k < 4; k++) {
        v1[k] = g1[(r * 4 + k) * NCH];
        v2[k] = g2[(r * 4 + k) * NCH];
    }
    #pragma unroll
    for (int j = 0; j < 5; j++) {
        const int q = NEG_IDX[r][j];
        #pragma unroll
        for (int k = 0; k < 4; k++) {
            n1[j][k] = g1[(q * 4 + k) * NCH];
            n2[j][k] = g2[(q * 4 + k) * NCH];
        }
    }

    const float nv1 = dot4(v1, v1);
    const float nv2 = dot4(v2, v2);

    float s = expf(10.0f * dot4(v1, v2) / fmaxf(sqrtf(nv1 * nv2), 1e-6f));
    float d1 = 0.0f, d2 = 0.0f;
    #pragma unroll
    for (int j = 0; j < 5; j++) {
        const float nn1 = dot4(n1[j], n1[j]);
        const float nn2 = dot4(n2[j], n2[j]);
        d1 += expf(10.0f * dot4(v1, n1[j]) / fmaxf(sqrtf(nv1 * nn1), 1e-6f));
        d1 += expf(10.0f * dot4(v1, n2[j]) / fmaxf(sqrtf(nv1 * nn2), 1e-6f));
        d2 += expf(10.0f * dot4(v2, n2[j]) / fmaxf(sqrtf(nv2 * nn2), 1e-6f));
        d2 += expf(10.0f * dot4(v2, n1[j]) / fmaxf(sqrtf(nv2 * nn1), 1e-6f));
    }

    s = wave_sum(s);
    d1 = wave_sum(d1);
    d2 = wave_sum(d2);

    __shared__ float sm[3][8];
    const int wave = threadIdx.x >> 6;
    const int lane = threadIdx.x & 63;
    if (lane == 0) { sm[0][wave] = s; sm[1][wave] = d1; sm[2][wave] = d2; }
    __syncthreads();
    if (threadIdx.x == 0) {
        float S = 0.0f, D1 = 0.0f, D2 = 0.0f;
        #pragma unroll
        for (int w = 0; w < 8; w++) { S += sm[0][w]; D1 += sm[1][w]; D2 += sm[2][w]; }
        terms[blk] = logf(S + D1) + logf(S + D2) - 2.0f * logf(S);
    }
}

// Phase C: reduce the 72 partial terms -> scalar loss / (B * N_REGIONS).
__global__ __launch_bounds__(64) void lcl_final(const float* __restrict__ terms,
                                                float* __restrict__ out) {
    const int t = threadIdx.x;  // 0..63
    float v = terms[t];
    if (t + 64 < NPAIR * NREG) v += terms[t + 64];
    v = wave_sum(v);
    if (t == 0) out[0] = v * (1.0f / 144.0f);
}

extern "C" void kernel_launch(void* const* d_in, const int* in_sizes, int n_in,
                              void* d_out, int out_size, void* d_ws, size_t ws_size,
                              hipStream_t stream) {
    const float* x = (const float*)d_in[0];
    float* out = (float*)d_out;
    float* g = (float*)d_ws;                 // 294912 floats
    float* terms = (float*)d_ws + G_FLOATS;  // 72 floats

    lcl_gather<<<(16 * NPATCH * NCH) / 256, 256, 0, stream>>>(x, g);
    lcl_partial<<<NPAIR * NREG, 512, 0, stream>>>(g, terms);
    lcl_final<<<1, 64, 0, stream>>>(terms, out);
}

// Round 3
// 160.283 us; speedup vs baseline: 1.0733x; 1.0086x over previous
//
#include <hip/hip_runtime.h>
#include <math.h>

// B=16, C=512, H=W=62, HW=3844, 9 regions, 5 negs/region, TEMP=0.1, EPS=1e-6.
#define NPAIR 8
#define NREG 9
#define NCH 512
#define HW 3844
#define W62 62
#define NPATCH 9

// The 9 unique patch base offsets (row*62+col). POS region r uses patch r;
// NEG bases are a subset of the same 9 -> indices below.
__constant__ int PATCH_BASE[9] = {0, 30, 60, 1860, 1890, 1920, 3720, 3750, 3780};
__constant__ int NEG_IDX[9][5] = {
    {1, 3, 4, 2, 6},
    {0, 2, 3, 4, 5},
    {0, 1, 4, 5, 8},
    {0, 1, 4, 6, 7},
    {0, 1, 3, 5, 7},
    {1, 2, 4, 7, 8},
    {0, 3, 4, 7, 8},
    {3, 4, 5, 6, 8},
    {2, 4, 5, 6, 7}};

__device__ __forceinline__ float dot4(const float4& a, const float4& b) {
    return a.x * b.x + a.y * b.y + a.z * b.z + a.w * b.w;
}

__device__ __forceinline__ float wave_sum(float v) {
    #pragma unroll
    for (int off = 32; off > 0; off >>= 1) v += __shfl_down(v, off, 64);
    return v;
}

// Phase A: gather the 36 used pixels of each (b,c) plane into compact layout
// g[b*9+patch][c][4] (channel-major, patch-pixels innermost -> float4 access).
// One thread per (b,patch,c); also zero-inits the output accumulator.
__global__ __launch_bounds__(256) void lcl_gather(const float* __restrict__ x,
                                                  float4* __restrict__ g,
                                                  float* __restrict__ out) {
    const int tid = blockIdx.x * 256 + threadIdx.x;  // 0..73727
    if (tid == 0) out[0] = 0.0f;  // ordered before lcl_partial (same stream)
    const int c = tid & (NCH - 1);
    const int bp = tid >> 9;  // b*9 + patch
    const int patch = bp % NPATCH;
    const int b = bp / NPATCH;
    const float* src = x + (size_t)(b * NCH + c) * HW + PATCH_BASE[patch];
    const float2 a0 = *(const float2*)(src);
    const float2 a1 = *(const float2*)(src + W62);
    g[(size_t)bp * NCH + c] = make_float4(a0.x, a0.y, a1.x, a1.y);
}

// Phase B: one block per (pair, region), thread = channel. 12 coalesced
// float4 loads per thread from L2-resident g; atomicAdd one term per block.
__global__ __launch_bounds__(512) void lcl_partial(const float4* __restrict__ g,
                                                   float* __restrict__ out) {
    const int blk = blockIdx.x;  // 0..71
    const int p = blk / NREG;
    const int r = blk % NREG;
    const int c = threadIdx.x;

    const float4* g1 = g + (size_t)(2 * p) * NPATCH * NCH + c;
    const float4* g2 = g + (size_t)(2 * p + 1) * NPATCH * NCH + c;

    const float4 v1 = g1[r * NCH];
    const float4 v2 = g2[r * NCH];
    const float nv1 = dot4(v1, v1);
    const float nv2 = dot4(v2, v2);

    float s = expf(10.0f * dot4(v1, v2) / fmaxf(sqrtf(nv1 * nv2), 1e-6f));
    float d1 = 0.0f, d2 = 0.0f;
    #pragma unroll
    for (int j = 0; j < 5; j++) {
        const int q = NEG_IDX[r][j];
        const float4 n1 = g1[q * NCH];
        const float4 n2 = g2[q * NCH];
        const float nn1 = dot4(n1, n1);
        const float nn2 = dot4(n2, n2);
        d1 += expf(10.0f * dot4(v1, n1) / fmaxf(sqrtf(nv1 * nn1), 1e-6f));
        d1 += expf(10.0f * dot4(v1, n2) / fmaxf(sqrtf(nv1 * nn2), 1e-6f));
        d2 += expf(10.0f * dot4(v2, n2) / fmaxf(sqrtf(nv2 * nn2), 1e-6f));
        d2 += expf(10.0f * dot4(v2, n1) / fmaxf(sqrtf(nv2 * nn1), 1e-6f));
    }

    s = wave_sum(s);
    d1 = wave_sum(d1);
    d2 = wave_sum(d2);

    __shared__ float sm[3][8];
    const int wave = threadIdx.x >> 6;
    const int lane = threadIdx.x & 63;
    if (lane == 0) { sm[0][wave] = s; sm[1][wave] = d1; sm[2][wave] = d2; }
    __syncthreads();
    if (threadIdx.x == 0) {
        float S = 0.0f, D1 = 0.0f, D2 = 0.0f;
        #pragma unroll
        for (int w = 0; w < 8; w++) { S += sm[0][w]; D1 += sm[1][w]; D2 += sm[2][w]; }
        const float term = logf(S + D1) + logf(S + D2) - 2.0f * logf(S);
        atomicAdd(out, term * (1.0f / 144.0f));
    }
}

extern "C" void kernel_launch(void* const* d_in, const int* in_sizes, int n_in,
                              void* d_out, int out_size, void* d_ws, size_t ws_size,
                              hipStream_t stream) {
    const float* x = (const float*)d_in[0];
    float* out = (float*)d_out;
    float4* g = (float4*)d_ws;  // 16*9*512 float4 = 1.18 MB

    lcl_gather<<<(16 * NPATCH * NCH) / 256, 256, 0, stream>>>(x, g, out);
    lcl_partial<<<NPAIR * NREG, 512, 0, stream>>>(g, out);
}